// Round 15
// baseline (60.435 us; speedup 1.0000x reference)
//
#include <hip/hip_runtime.h>
#include <hip/hip_bf16.h>

#define KDIM  1024
#define NTOK  8192
#define NCB   16

typedef __attribute__((ext_vector_type(8))) short short8;
typedef __attribute__((ext_vector_type(4))) float f32x4;

__device__ static inline unsigned short f2bf(float f) {
    unsigned int u = __float_as_uint(f);
    return (unsigned short)((u + 0x7FFFu + ((u >> 16) & 1u)) >> 16);
}

// ---- convert + re-layout ----
// A2: bf16, [tokTile=256][kt=32][tok32][kk32] ; elem = tile*32768 + kt*1024 + (tok&31)*32 + kk
// Bt2: bf16, [kt=32][n=1024][kk=32]          ; elem = kt*32768 + n*32 + kk   (n = h*64+o)
__global__ __launch_bounds__(256) void conv_kernel(const float* __restrict__ x,
                                                   const float* __restrict__ W,
                                                   unsigned short* __restrict__ A2,
                                                   unsigned short* __restrict__ Bt2) {
    int b = blockIdx.x;
    if (b < 4096) {
        int bb = (b & 7) * 512 + (b >> 3);    // token-panel p -> XCD p (matches fused)
        int u = bb * 256 + threadIdx.x;
        int tok = u >> 7;                     // 128 threads/token
        int k0  = (u & 127) * 8;
        const float* src = x + (size_t)tok * KDIM + k0;
        float4 v0 = *(const float4*)(src);
        float4 v1 = *(const float4*)(src + 4);
        short8 o;
        o[0] = (short)f2bf(v0.x); o[1] = (short)f2bf(v0.y);
        o[2] = (short)f2bf(v0.z); o[3] = (short)f2bf(v0.w);
        o[4] = (short)f2bf(v1.x); o[5] = (short)f2bf(v1.y);
        o[6] = (short)f2bf(v1.z); o[7] = (short)f2bf(v1.w);
        size_t dst = (size_t)(tok >> 5) * 32768 + (size_t)(k0 >> 5) * 1024
                   + (tok & 31) * 32 + (k0 & 31);
        *(short8*)(A2 + dst) = o;
    } else {
        int u = (b - 4096) * 256 + threadIdx.x;
        int n  = u & 1023;
        int k0 = (u >> 10) << 3;
        int h = n >> 6, o = n & 63;
        const float* src = W + (size_t)h * KDIM * 64 + o;
        short8 v;
#pragma unroll
        for (int j = 0; j < 8; ++j)
            v[j] = (short)f2bf(src[(size_t)(k0 + j) * 64]);
        size_t dst = (size_t)(k0 >> 5) * 32768 + (size_t)n * 32 + (k0 & 31);
        *(short8*)(Bt2 + dst) = v;
    }
}

// ---- fused GEMM + outer-product + mean + rms_norm ----
// 256 blocks (1/CU), 512 thr = 8 waves. Block owns 32 tokens x ALL 1024 cols;
// wave w owns cols [w*128, w*128+128) = codebooks 2w,2w+1.
// K-loop is barrier-free and LDS-free: per tile, 2 a-frag + 8 b-frag loads go
// global->VGPR (each a perfectly coalesced 1KB wave read thanks to the k-slab
// layout), 1-tile-deep prefetch, vmcnt(10), 16 MFMA. acc[2][8] f32x4.
__global__ __launch_bounds__(512, 2) void fused_kernel(const unsigned short* __restrict__ A2,
                                                       const unsigned short* __restrict__ Bt2,
                                                       float* __restrict__ out) {
    extern __shared__ float ylds[];   // [32][1028] f32 = 131584 B

    const int id = blockIdx.x;
    const int tokTile = (id & 7) * 32 + (id >> 3);   // XCD-aligned with conv

    const int tid  = threadIdx.x;
    const int lane = tid & 63;
    const int w    = tid >> 6;
    const int r15  = lane & 15;
    const int q    = lane >> 4;

    const unsigned short* abase = A2 + (size_t)tokTile * 32768 + r15 * 32 + q * 8;
    const unsigned short* bbase = Bt2 + (size_t)(w * 128 + r15) * 32 + q * 8;

    f32x4 acc[2][8];
#pragma unroll
    for (int mf = 0; mf < 2; ++mf)
#pragma unroll
        for (int nf = 0; nf < 8; ++nf)
            acc[mf][nf] = (f32x4){0.f, 0.f, 0.f, 0.f};

    short8 aA[2], bA[8], aB[2], bB[8];

    // prologue: tile 0 -> set A
#pragma unroll
    for (int mf = 0; mf < 2; ++mf)
        aA[mf] = *(const short8*)(abase + mf * 512);
#pragma unroll
    for (int nf = 0; nf < 8; ++nf)
        bA[nf] = *(const short8*)(bbase + nf * 512);

#pragma unroll 1
    for (int t2 = 0; t2 < 16; ++t2) {
        // even tile t=2*t2: cur=A, prefetch tile t+1 -> B
        {
            const int tn = 2 * t2 + 1;
#pragma unroll
            for (int mf = 0; mf < 2; ++mf)
                aB[mf] = *(const short8*)(abase + tn * 1024 + mf * 512);
#pragma unroll
            for (int nf = 0; nf < 8; ++nf)
                bB[nf] = *(const short8*)(bbase + (size_t)tn * 32768 + nf * 512);
            asm volatile("s_waitcnt vmcnt(10)" ::: "memory");
            __builtin_amdgcn_sched_barrier(0);
#pragma unroll
            for (int mf = 0; mf < 2; ++mf)
#pragma unroll
                for (int nf = 0; nf < 8; ++nf)
                    acc[mf][nf] = __builtin_amdgcn_mfma_f32_16x16x32_bf16(aA[mf], bA[nf], acc[mf][nf], 0, 0, 0);
        }
        // odd tile t=2*t2+1: cur=B, prefetch tile t+1 -> A
        {
            if (t2 < 15) {
                const int tn = 2 * t2 + 2;
#pragma unroll
                for (int mf = 0; mf < 2; ++mf)
                    aA[mf] = *(const short8*)(abase + tn * 1024 + mf * 512);
#pragma unroll
                for (int nf = 0; nf < 8; ++nf)
                    bA[nf] = *(const short8*)(bbase + (size_t)tn * 32768 + nf * 512);
                asm volatile("s_waitcnt vmcnt(10)" ::: "memory");
            } else {
                asm volatile("s_waitcnt vmcnt(0)" ::: "memory");
            }
            __builtin_amdgcn_sched_barrier(0);
#pragma unroll
            for (int mf = 0; mf < 2; ++mf)
#pragma unroll
                for (int nf = 0; nf < 8; ++nf)
                    acc[mf][nf] = __builtin_amdgcn_mfma_f32_16x16x32_bf16(aB[mf], bB[nf], acc[mf][nf], 0, 0, 0);
        }
    }

    // ---- in-block epilogue ----
    // y -> LDS: D layout col=lane&15, row=(lane>>4)*4+r
#pragma unroll
    for (int mf = 0; mf < 2; ++mf)
#pragma unroll
        for (int nf = 0; nf < 8; ++nf) {
            int col = w * 128 + nf * 16 + r15;
#pragma unroll
            for (int r = 0; r < 4; ++r)
                ylds[(mf * 16 + q * 4 + r) * 1028 + col] = acc[mf][nf][r];
        }
    __syncthreads();

    // outer product + mean*sqrt(16) + rms; 16 threads/token, 8x8 tile each (R2-verified)
    const int tok = tid >> 4;
    const int qq  = tid & 15;
    const int j0  = (qq >> 2) * 8;
    const int k0  = (qq & 3) * 8;
    const float* yr = ylds + tok * 1028;

    float o[8][8];
#pragma unroll
    for (int j = 0; j < 8; ++j)
#pragma unroll
        for (int k = 0; k < 8; ++k) o[j][k] = 0.f;

#pragma unroll
    for (int h = 0; h < NCB; ++h) {
        float4 a0 = *(const float4*)(yr + h * 64 + j0);
        float4 a1 = *(const float4*)(yr + h * 64 + j0 + 4);
        float4 b0 = *(const float4*)(yr + h * 64 + 32 + k0);
        float4 b1 = *(const float4*)(yr + h * 64 + 32 + k0 + 4);
        float aa[8] = {a0.x, a0.y, a0.z, a0.w, a1.x, a1.y, a1.z, a1.w};
        float bb[8] = {b0.x, b0.y, b0.z, b0.w, b1.x, b1.y, b1.z, b1.w};
#pragma unroll
        for (int j = 0; j < 8; ++j)
#pragma unroll
            for (int k = 0; k < 8; ++k)
                o[j][k] += aa[j] * bb[k];
    }

    float ss = 0.f;
#pragma unroll
    for (int j = 0; j < 8; ++j)
#pragma unroll
        for (int k = 0; k < 8; ++k) {
            o[j][k] *= 0.25f;                 // mean over 16 cb * sqrt(16)
            ss += o[j][k] * o[j][k];
        }
#pragma unroll
    for (int off = 1; off < 16; off <<= 1)    // reduce over the token's 16 lanes
        ss += __shfl_xor(ss, off, 64);
    const float scale = rsqrtf(ss * (1.0f / 1024.0f) + 1e-12f);

    float* orow = out + (size_t)(tokTile * 32 + tok) * 1024 + k0;
#pragma unroll
    for (int j = 0; j < 8; ++j) {
        float4 w0, w1;
        w0.x = o[j][0] * scale; w0.y = o[j][1] * scale; w0.z = o[j][2] * scale; w0.w = o[j][3] * scale;
        w1.x = o[j][4] * scale; w1.y = o[j][5] * scale; w1.z = o[j][6] * scale; w1.w = o[j][7] * scale;
        *(float4*)(orow + (j0 + j) * 32)     = w0;
        *(float4*)(orow + (j0 + j) * 32 + 4) = w1;
    }
}

extern "C" void kernel_launch(void* const* d_in, const int* in_sizes, int n_in,
                              void* d_out, int out_size, void* d_ws, size_t ws_size,
                              hipStream_t stream) {
    const float* x   = (const float*)d_in[0];
    const float* wgt = (const float*)d_in[1];
    float* out = (float*)d_out;

    unsigned short* A2  = (unsigned short*)d_ws;                        // 16 MB
    unsigned short* Bt2 = (unsigned short*)((char*)d_ws + (16u << 20)); //  2 MB

    (void)hipFuncSetAttribute((const void*)fused_kernel,
                              hipFuncAttributeMaxDynamicSharedMemorySize, 131584);

    conv_kernel<<<4096 + 512, 256, 0, stream>>>(x, wgt, A2, Bt2);
    fused_kernel<<<256, 512, 131584, stream>>>(A2, Bt2, out);
}

// Round 16
// 53.001 us; speedup vs baseline: 1.1403x; 1.1403x over previous
//
#include <hip/hip_runtime.h>
#include <hip/hip_bf16.h>

#define KDIM  1024
#define NOUT  1024
#define NTOK  8192
#define NCB   16
#define BM    256
#define BN    128
#define BK    64
#define BBUF  16384   // one B K-tile buffer: 128 x 64 bf16
#define NBUF  3

typedef __attribute__((ext_vector_type(8))) short short8;
typedef __attribute__((ext_vector_type(4))) float f32x4;

__device__ static inline unsigned short f2bf(float f) {
    unsigned int u = __float_as_uint(f);
    return (unsigned short)((u + 0x7FFFu + ((u >> 16) & 1u)) >> 16);
}

__device__ static inline float bf2f(unsigned int h) {
    return __uint_as_float(h << 16);
}

__device__ static inline void async_copy16(const void* g, void* l) {
    __builtin_amdgcn_global_load_lds(
        (const __attribute__((address_space(1))) void*)g,
        (__attribute__((address_space(3))) void*)l, 16, 0, 0);
}

// opaque 16B global load -> VGPRs; compiler does NOT track the latency, our
// counted vmcnt is the only wait (HK pattern). Issue order = program order.
__device__ __forceinline__ short8 gload16(const unsigned short* p) {
    short8 d;
    asm volatile("global_load_dwordx4 %0, %1, off" : "=v"(d) : "v"(p) : "memory");
    return d;
}

// ---- convert: x -> A2 k-slab layout (R15-verified), W -> Bt [n][k] ----
// A2 elem = (tok>>5)*32768 + (k>>5)*1024 + (tok&31)*32 + (k&31)
__global__ __launch_bounds__(256) void conv_kernel(const float* __restrict__ x,
                                                   const float* __restrict__ W,
                                                   unsigned short* __restrict__ A2,
                                                   unsigned short* __restrict__ Bt) {
    int b = blockIdx.x;
    if (b < 4096) {
        int bb = (b & 7) * 512 + (b >> 3);    // token-panel p -> XCD p (matches gemm)
        int u = bb * 256 + threadIdx.x;
        int tok = u >> 7;                     // 128 threads/token
        int k0  = (u & 127) * 8;
        const float* src = x + (size_t)tok * KDIM + k0;
        float4 v0 = *(const float4*)(src);
        float4 v1 = *(const float4*)(src + 4);
        short8 o;
        o[0] = (short)f2bf(v0.x); o[1] = (short)f2bf(v0.y);
        o[2] = (short)f2bf(v0.z); o[3] = (short)f2bf(v0.w);
        o[4] = (short)f2bf(v1.x); o[5] = (short)f2bf(v1.y);
        o[6] = (short)f2bf(v1.z); o[7] = (short)f2bf(v1.w);
        size_t dst = (size_t)(tok >> 5) * 32768 + (size_t)(k0 >> 5) * 1024
                   + (tok & 31) * 32 + (k0 & 31);
        *(short8*)(A2 + dst) = o;
    } else {
        int u = (b - 4096) * 256 + threadIdx.x;
        int n  = u & (NOUT - 1);
        int k0 = (u >> 10) << 3;
        int h = n >> 6, o = n & 63;
        const float* src = W + (size_t)h * KDIM * 64 + o;
        short8 v;
#pragma unroll
        for (int j = 0; j < 8; ++j)
            v[j] = (short)f2bf(src[(size_t)(k0 + j) * 64]);
        *(short8*)(Bt + (size_t)n * KDIM + k0) = v;
    }
}

// B K-tile stage (gload_lds, linear dest, XOR chunk-swizzle in global source)
__device__ __forceinline__ void stage_b(const unsigned short* __restrict__ Bt,
                                        char* lbase, int tid, int n0, int kel) {
    unsigned short* Bls = (unsigned short*)lbase;
#pragma unroll
    for (int i = 0; i < 2; ++i) {
        int s = i * 512 + tid;
        int row = s >> 3;
        int cs = (s & 7) ^ (row & 7);
        async_copy16(Bt + (size_t)(n0 + row) * KDIM + kel + cs * 8, Bls + s * 8);
    }
}

__device__ __forceinline__ void mfma16(short8 (&af)[4], short8 (&bf)[4], f32x4 (&acc)[4][4]) {
    __builtin_amdgcn_s_setprio(1);
#pragma unroll
    for (int mf = 0; mf < 4; ++mf)
#pragma unroll
        for (int nf = 0; nf < 4; ++nf)
            acc[mf][nf] = __builtin_amdgcn_mfma_f32_16x16x32_bf16(af[mf], bf[nf], acc[mf][nf], 0, 0, 0);
    __builtin_amdgcn_s_setprio(0);
}

// one K-tile, single barrier. FIFO batch per tile: [A(t+1) x8, Bstage(t+2) x2]
// -> steady vmcnt(2) retires exactly A(t)+B(t).
template <int VM, bool IA, bool IB>
__device__ __forceinline__ void ktile(const unsigned short* const (&ap)[4],
                                      const unsigned short* __restrict__ Bt,
                                      char* lds, int tid, int n0, int kt,
                                      int wn, int r15, int q,
                                      short8 (&aC)[4][2], short8 (&aN)[4][2],
                                      f32x4 (&acc)[4][4]) {
    asm volatile("s_waitcnt vmcnt(%0)" :: "i"(VM) : "memory");
    __builtin_amdgcn_sched_barrier(0);
    __builtin_amdgcn_s_barrier();
    __builtin_amdgcn_sched_barrier(0);

    const unsigned short* Bl = (const unsigned short*)(lds + (kt % NBUF) * BBUF);
    short8 bf0[4], bf1[4];
#pragma unroll
    for (int nf = 0; nf < 4; ++nf) {
        int row = wn * 64 + nf * 16 + r15;
        bf0[nf] = *(const short8*)(Bl + row * 64 + ((q ^ (row & 7)) << 3));
    }
#pragma unroll
    for (int nf = 0; nf < 4; ++nf) {
        int row = wn * 64 + nf * 16 + r15;
        bf1[nf] = *(const short8*)(Bl + row * 64 + (((4 + q) ^ (row & 7)) << 3));
    }
    __builtin_amdgcn_sched_barrier(0);
    if (IA) {
#pragma unroll
        for (int mf = 0; mf < 4; ++mf)
#pragma unroll
            for (int h = 0; h < 2; ++h)
                aN[mf][h] = gload16(ap[mf] + (2 * (kt + 1) + h) * 1024);
    }
    __builtin_amdgcn_sched_barrier(0);
    if (IB)
        stage_b(Bt, lds + ((kt + 2) % NBUF) * BBUF, tid, n0, (kt + 2) * BK);

    asm volatile("s_waitcnt lgkmcnt(4)" ::: "memory");
    __builtin_amdgcn_sched_barrier(0);
    short8 a0[4] = {aC[0][0], aC[1][0], aC[2][0], aC[3][0]};
    mfma16(a0, bf0, acc);
    asm volatile("s_waitcnt lgkmcnt(0)" ::: "memory");
    __builtin_amdgcn_sched_barrier(0);
    short8 a1[4] = {aC[0][1], aC[1][1], aC[2][1], aC[3][1]};
    mfma16(a1, bf1, acc);
}

// ---- GEMM: BM=256 BN=128, 8 waves (4M x 2N). A global->reg (k-slab layout,
// 1-tile prefetch, asm loads); B via NBUF=3 swizzled LDS pipeline. ----
__global__ __launch_bounds__(512, 2) void gemm_kernel(const unsigned short* __restrict__ A2,
                                                      const unsigned short* __restrict__ Bt,
                                                      unsigned short* __restrict__ Y) {
    __shared__ char lds[NBUF * BBUF];   // 48 KB

    const int id  = blockIdx.x;
    const int xcd = id & 7;
    const int j   = id >> 3;                  // 0..31
    const int m0  = (xcd * 4 + (j >> 3)) * BM;
    const int n0  = (j & 7) * BN;
    const int Gb  = m0 >> 5;                  // granule base

    const int tid  = threadIdx.x;
    const int lane = tid & 63;
    const int w    = tid >> 6;
    const int wm   = w >> 1;
    const int wn   = w & 1;
    const int r15  = lane & 15;
    const int q    = lane >> 4;

    // per-mf A pointers: granule Gb+2wm+(mf>>1), token (mf&1)*16+r15, kk q*8
    const unsigned short* ap[4];
#pragma unroll
    for (int mf = 0; mf < 4; ++mf)
        ap[mf] = A2 + (size_t)(Gb + 2 * wm + (mf >> 1)) * 32768
               + ((mf & 1) * 16 + r15) * 32 + q * 8;

    f32x4 acc[4][4];
#pragma unroll
    for (int mf = 0; mf < 4; ++mf)
#pragma unroll
        for (int nf = 0; nf < 4; ++nf)
            acc[mf][nf] = (f32x4){0.f, 0.f, 0.f, 0.f};

    short8 aC[4][2], aN[4][2];

    // prologue FIFO: [A(0) x8, B(0) x2, B(1) x2]
#pragma unroll
    for (int mf = 0; mf < 4; ++mf)
#pragma unroll
        for (int h = 0; h < 2; ++h)
            aC[mf][h] = gload16(ap[mf] + h * 1024);
    __builtin_amdgcn_sched_barrier(0);
    stage_b(Bt, lds,        tid, n0, 0);
    stage_b(Bt, lds + BBUF, tid, n0, BK);

#pragma unroll 1
    for (int t2 = 0; t2 < 7; ++t2) {
        ktile<2, true, true>(ap, Bt, lds, tid, n0, 2 * t2,     wn, r15, q, aC, aN, acc);
        ktile<2, true, true>(ap, Bt, lds, tid, n0, 2 * t2 + 1, wn, r15, q, aN, aC, acc);
    }
    ktile<2, true,  false>(ap, Bt, lds, tid, n0, 14, wn, r15, q, aC, aN, acc);
    ktile<0, false, false>(ap, Bt, lds, tid, n0, 15, wn, r15, q, aN, aC, acc);

    // write back: D layout col=lane&15, row=(lane>>4)*4+r
#pragma unroll
    for (int mf = 0; mf < 4; ++mf)
#pragma unroll
        for (int nf = 0; nf < 4; ++nf) {
            int col = n0 + wn * 64 + nf * 16 + r15;
#pragma unroll
            for (int r = 0; r < 4; ++r) {
                int row = m0 + wm * 64 + mf * 16 + q * 4 + r;
                Y[(size_t)row * NOUT + col] = f2bf(acc[mf][nf][r]);
            }
        }
}

// ---- epilogue: outer product + mean*sqrt(h) + rms_norm; 1 block/token,
// XCD-aligned: token t runs on XCD t>>10, where its Y rows were produced. ----
__global__ __launch_bounds__(256) void epilogue_kernel(const unsigned short* __restrict__ Y,
                                                       float* __restrict__ out) {
    __shared__ float ylds[1024];
    __shared__ float red[4];

    const int t = (blockIdx.x & 7) * 1024 + (blockIdx.x >> 3);
    const int tid = threadIdx.x;
    const unsigned short* yrow = Y + (size_t)t * NOUT;

    {
        uint2 raw = *(const uint2*)(yrow + tid * 4);
        ylds[tid * 4 + 0] = bf2f(raw.x & 0xffffu);
        ylds[tid * 4 + 1] = bf2f(raw.x >> 16);
        ylds[tid * 4 + 2] = bf2f(raw.y & 0xffffu);
        ylds[tid * 4 + 3] = bf2f(raw.y >> 16);
    }
    __syncthreads();

    const int jj = tid >> 3;
    const int k0 = (tid & 7) * 4;

    float o0 = 0.f, o1 = 0.f, o2 = 0.f, o3 = 0.f;
#pragma unroll
    for (int h = 0; h < NCB; ++h) {
        float a = ylds[h * 64 + jj];
        float4 bb = *(const float4*)&ylds[h * 64 + 32 + k0];
        o0 += a * bb.x; o1 += a * bb.y; o2 += a * bb.z; o3 += a * bb.w;
    }
    o0 *= 0.25f; o1 *= 0.25f; o2 *= 0.25f; o3 *= 0.25f;

    float ss = o0 * o0 + o1 * o1 + o2 * o2 + o3 * o3;
#pragma unroll
    for (int off = 32; off >= 1; off >>= 1)
        ss += __shfl_xor(ss, off, 64);

    const int lane = tid & 63, wv = tid >> 6;
    if (lane == 0) red[wv] = ss;
    __syncthreads();
    float tot = red[0] + red[1] + red[2] + red[3];
    float scale = rsqrtf(tot * (1.0f / 1024.0f) + 1e-12f);

    float4 o;
    o.x = o0 * scale; o.y = o1 * scale; o.z = o2 * scale; o.w = o3 * scale;
    *(float4*)(out + (size_t)t * 1024 + tid * 4) = o;
}

extern "C" void kernel_launch(void* const* d_in, const int* in_sizes, int n_in,
                              void* d_out, int out_size, void* d_ws, size_t ws_size,
                              hipStream_t stream) {
    const float* x   = (const float*)d_in[0];
    const float* wgt = (const float*)d_in[1];
    float* out = (float*)d_out;

    unsigned short* A2 = (unsigned short*)d_ws;                        // 16 MB
    unsigned short* Bt = (unsigned short*)((char*)d_ws + (16u << 20)); //  2 MB
    unsigned short* Y  = (unsigned short*)((char*)d_ws + (18u << 20)); // 16 MB

    conv_kernel<<<4096 + 512, 256, 0, stream>>>(x, wgt, A2, Bt);
    gemm_kernel<<<(NTOK / BM) * (NOUT / BN), 512, 0, stream>>>(A2, Bt, Y);
    epilogue_kernel<<<NTOK, 256, 0, stream>>>(Y, out);
}

// Round 17
// 46.899 us; speedup vs baseline: 1.2886x; 1.1301x over previous
//
#include <hip/hip_runtime.h>
#include <hip/hip_bf16.h>

#define KDIM  1024
#define NOUT  1024
#define NTOK  8192
#define NCB   16
#define BM    256
#define BN    128
#define BK    64
#define TILEB 49152   // A 32KB + B 16KB per K-tile buffer
#define NBUF  3

typedef __attribute__((ext_vector_type(8))) short short8;
typedef __attribute__((ext_vector_type(4))) float f32x4;

__device__ static inline unsigned short f2bf(float f) {
    unsigned int u = __float_as_uint(f);
    return (unsigned short)((u + 0x7FFFu + ((u >> 16) & 1u)) >> 16);
}

__device__ static inline float bf2f(unsigned int h) {
    return __uint_as_float(h << 16);
}

__device__ static inline void async_copy16(const void* g, void* l) {
    __builtin_amdgcn_global_load_lds(
        (const __attribute__((address_space(1))) void*)g,
        (__attribute__((address_space(3))) void*)l, 16, 0, 0);
}

// ---- combined convert: x->A (XCD-aligned with gemm m-panels), W->Bt ----
__global__ __launch_bounds__(256) void conv_kernel(const float* __restrict__ x,
                                                   const float* __restrict__ W,
                                                   unsigned short* __restrict__ A,
                                                   unsigned short* __restrict__ Bt) {
    int b = blockIdx.x;
    if (b < 4096) {
        int bb = (b & 7) * 512 + (b >> 3);   // token-panel p -> XCD p (matches gemm)
        int u = bb * 256 + threadIdx.x;
        const float* src = x + (size_t)u * 8;
        float4 v0 = *(const float4*)(src);
        float4 v1 = *(const float4*)(src + 4);
        short8 o;
        o[0] = (short)f2bf(v0.x); o[1] = (short)f2bf(v0.y);
        o[2] = (short)f2bf(v0.z); o[3] = (short)f2bf(v0.w);
        o[4] = (short)f2bf(v1.x); o[5] = (short)f2bf(v1.y);
        o[6] = (short)f2bf(v1.z); o[7] = (short)f2bf(v1.w);
        *(short8*)(A + (size_t)u * 8) = o;
    } else {
        int u = (b - 4096) * 256 + threadIdx.x;
        int n  = u & (NOUT - 1);
        int k0 = (u >> 10) << 3;
        int h = n >> 6, o = n & 63;
        const float* src = W + (size_t)h * KDIM * 64 + o;
        short8 v;
#pragma unroll
        for (int j = 0; j < 8; ++j)
            v[j] = (short)f2bf(src[(size_t)(k0 + j) * 64]);
        *(short8*)(Bt + (size_t)n * KDIM + k0) = v;
    }
}

// ---- GEMM: BM=256 BN=128 BK=64, 512 thr (8 waves 4Mx2N), NBUF=3.
// Single barrier per K-tile + CROSS-TILE register prefetch:
// enter tile t with h0(t) frags in F0 (issued one tile ago). Body:
// [vmcnt(6); bar; read h1(t)->F1; stage(t+2); lgkm(8) {retires F0's old reads};
//  MFMA h0(F0); vmcnt(6) {t+1 landed}; read h0(t+1)->F0; lgkm(8) {retires F1};
//  MFMA h1(F1)]. All lgkm waits target reads issued >=16 MFMA earlier.

__device__ __forceinline__ void stage_tile(const unsigned short* __restrict__ A,
                                           const unsigned short* __restrict__ Bt,
                                           char* lbase, int tid, int m0, int n0, int kel) {
    unsigned short* Als = (unsigned short*)lbase;
    unsigned short* Bls = (unsigned short*)(lbase + 32768);
#pragma unroll
    for (int i = 0; i < 4; ++i) {
        int s = i * 512 + tid;
        int row = s >> 3;
        int cs = (s & 7) ^ (row & 7);
        async_copy16(A + (size_t)(m0 + row) * KDIM + kel + cs * 8, Als + s * 8);
    }
#pragma unroll
    for (int i = 0; i < 2; ++i) {
        int s = i * 512 + tid;
        int row = s >> 3;
        int cs = (s & 7) ^ (row & 7);
        async_copy16(Bt + (size_t)(n0 + row) * KDIM + kel + cs * 8, Bls + s * 8);
    }
}

__device__ __forceinline__ void read_frags(const char* lds, int buf, int chunk,
                                           int wm, int wn, int r15, int q,
                                           short8 (&af)[4], short8 (&bf)[4]) {
    const unsigned short* Al = (const unsigned short*)(lds + buf * TILEB);
    const unsigned short* Bl = Al + 16384;
#pragma unroll
    for (int mf = 0; mf < 4; ++mf) {
        int row = wm * 64 + mf * 16 + r15;
        af[mf] = *(const short8*)(Al + row * 64 + (((chunk + q) ^ (row & 7)) << 3));
    }
#pragma unroll
    for (int nf = 0; nf < 4; ++nf) {
        int row = wn * 64 + nf * 16 + r15;
        bf[nf] = *(const short8*)(Bl + row * 64 + (((chunk + q) ^ (row & 7)) << 3));
    }
}

__device__ __forceinline__ void mfma16(short8 (&af)[4], short8 (&bf)[4], f32x4 (&acc)[4][4]) {
    __builtin_amdgcn_s_setprio(1);
#pragma unroll
    for (int mf = 0; mf < 4; ++mf)
#pragma unroll
        for (int nf = 0; nf < 4; ++nf)
            acc[mf][nf] = __builtin_amdgcn_mfma_f32_16x16x32_bf16(af[mf], bf[nf], acc[mf][nf], 0, 0, 0);
    __builtin_amdgcn_s_setprio(0);
}

// one K-tile, single barrier, cross-tile F0 prefetch.
// VM1: retires tile t's stages. VM2: retires tile t+1's stages (for PRE read).
template <int VM1, int VM2, bool STAGE, bool PRE>
__device__ __forceinline__ void ktile(const unsigned short* __restrict__ A,
                                      const unsigned short* __restrict__ Bt,
                                      char* lds, int tid, int m0, int n0, int kt,
                                      int wm, int wn, int r15, int q,
                                      short8 (&aF0)[4], short8 (&bF0)[4],
                                      short8 (&aF1)[4], short8 (&bF1)[4],
                                      f32x4 (&acc)[4][4]) {
    asm volatile("s_waitcnt vmcnt(%0)" :: "i"(VM1) : "memory");
    __builtin_amdgcn_sched_barrier(0);
    __builtin_amdgcn_s_barrier();
    __builtin_amdgcn_sched_barrier(0);
    read_frags(lds, kt % NBUF, 4, wm, wn, r15, q, aF1, bF1);   // h1(t)
    if (STAGE)
        stage_tile(A, Bt, lds + ((kt + 2) % NBUF) * TILEB, tid, m0, n0, (kt + 2) * BK);
    asm volatile("s_waitcnt lgkmcnt(8)" ::: "memory");         // retire F0 (old)
    __builtin_amdgcn_sched_barrier(0);
    mfma16(aF0, bF0, acc);                                     // h0(t)
    asm volatile("s_waitcnt vmcnt(%0)" :: "i"(VM2) : "memory");// t+1 landed
    __builtin_amdgcn_sched_barrier(0);
    if (PRE) {
        read_frags(lds, (kt + 1) % NBUF, 0, wm, wn, r15, q, aF0, bF0);  // h0(t+1)
        asm volatile("s_waitcnt lgkmcnt(8)" ::: "memory");     // retire F1
    } else {
        asm volatile("s_waitcnt lgkmcnt(0)" ::: "memory");
    }
    __builtin_amdgcn_sched_barrier(0);
    mfma16(aF1, bF1, acc);                                     // h1(t)
}

__global__ __launch_bounds__(512, 2) void gemm_kernel(const unsigned short* __restrict__ A,
                                                      const unsigned short* __restrict__ Bt,
                                                      unsigned short* __restrict__ Y) {
    extern __shared__ char lds[];   // 3 * 48KB

    const int id  = blockIdx.x;
    const int xcd = id & 7;
    const int j   = id >> 3;                  // 0..31
    const int m0  = (xcd * 4 + (j >> 3)) * BM;
    const int n0  = (j & 7) * BN;

    const int tid  = threadIdx.x;
    const int lane = tid & 63;
    const int w    = tid >> 6;
    const int wm   = w >> 1;
    const int wn   = w & 1;
    const int r15  = lane & 15;
    const int q    = lane >> 4;

    f32x4 acc[4][4];
#pragma unroll
    for (int mf = 0; mf < 4; ++mf)
#pragma unroll
        for (int nf = 0; nf < 4; ++nf)
            acc[mf][nf] = (f32x4){0.f, 0.f, 0.f, 0.f};

    short8 aF0[4], bF0[4], aF1[4], bF1[4];

    // prologue: tiles 0,1 in flight; h0(0) prefetched into F0
    stage_tile(A, Bt, lds,         tid, m0, n0, 0);
    stage_tile(A, Bt, lds + TILEB, tid, m0, n0, BK);
    asm volatile("s_waitcnt vmcnt(6)" ::: "memory");   // tile 0 landed
    __builtin_amdgcn_sched_barrier(0);
    __builtin_amdgcn_s_barrier();
    read_frags(lds, 0, 0, wm, wn, r15, q, aF0, bF0);

#pragma unroll 1
    for (int kt = 0; kt < 14; ++kt)
        ktile<6, 6, true, true>(A, Bt, lds, tid, m0, n0, kt, wm, wn, r15, q,
                                aF0, bF0, aF1, bF1, acc);
    ktile<6, 0, false, true >(A, Bt, lds, tid, m0, n0, 14, wm, wn, r15, q,
                              aF0, bF0, aF1, bF1, acc);
    ktile<0, 0, false, false>(A, Bt, lds, tid, m0, n0, 15, wm, wn, r15, q,
                              aF0, bF0, aF1, bF1, acc);

    // write back: D layout col=lane&15, row=(lane>>4)*4+r
#pragma unroll
    for (int mf = 0; mf < 4; ++mf)
#pragma unroll
        for (int nf = 0; nf < 4; ++nf) {
            int col = n0 + wn * 64 + nf * 16 + r15;
#pragma unroll
            for (int r = 0; r < 4; ++r) {
                int row = m0 + wm * 64 + mf * 16 + q * 4 + r;
                Y[(size_t)row * NOUT + col] = f2bf(acc[mf][nf][r]);
            }
        }
}

// ---- epilogue: outer product + mean*sqrt(h) + rms_norm; 1 block/token,
// XCD-aligned: token t runs on XCD t>>10, where its Y rows were produced. ----
__global__ __launch_bounds__(256) void epilogue_kernel(const unsigned short* __restrict__ Y,
                                                       float* __restrict__ out) {
    __shared__ float ylds[1024];
    __shared__ float red[4];

    const int t = (blockIdx.x & 7) * 1024 + (blockIdx.x >> 3);
    const int tid = threadIdx.x;
    const unsigned short* yrow = Y + (size_t)t * NOUT;

    {
        uint2 raw = *(const uint2*)(yrow + tid * 4);
        ylds[tid * 4 + 0] = bf2f(raw.x & 0xffffu);
        ylds[tid * 4 + 1] = bf2f(raw.x >> 16);
        ylds[tid * 4 + 2] = bf2f(raw.y & 0xffffu);
        ylds[tid * 4 + 3] = bf2f(raw.y >> 16);
    }
    __syncthreads();

    const int jj = tid >> 3;
    const int k0 = (tid & 7) * 4;

    float o0 = 0.f, o1 = 0.f, o2 = 0.f, o3 = 0.f;
#pragma unroll
    for (int h = 0; h < NCB; ++h) {
        float a = ylds[h * 64 + jj];
        float4 bb = *(const float4*)&ylds[h * 64 + 32 + k0];
        o0 += a * bb.x; o1 += a * bb.y; o2 += a * bb.z; o3 += a * bb.w;
    }
    o0 *= 0.25f; o1 *= 0.25f; o2 *= 0.25f; o3 *= 0.25f;

    float ss = o0 * o0 + o1 * o1 + o2 * o2 + o3 * o3;
#pragma unroll
    for (int off = 32; off >= 1; off >>= 1)
        ss += __shfl_xor(ss, off, 64);

    const int lane = tid & 63, wv = tid >> 6;
    if (lane == 0) red[wv] = ss;
    __syncthreads();
    float tot = red[0] + red[1] + red[2] + red[3];
    float scale = rsqrtf(tot * (1.0f / 1024.0f) + 1e-12f);

    float4 o;
    o.x = o0 * scale; o.y = o1 * scale; o.z = o2 * scale; o.w = o3 * scale;
    *(float4*)(out + (size_t)t * 1024 + tid * 4) = o;
}

extern "C" void kernel_launch(void* const* d_in, const int* in_sizes, int n_in,
                              void* d_out, int out_size, void* d_ws, size_t ws_size,
                              hipStream_t stream) {
    const float* x   = (const float*)d_in[0];
    const float* wgt = (const float*)d_in[1];
    float* out = (float*)d_out;

    unsigned short* A  = (unsigned short*)d_ws;                        // 16 MB
    unsigned short* Bt = (unsigned short*)((char*)d_ws + (16u << 20)); //  2 MB
    unsigned short* Y  = (unsigned short*)((char*)d_ws + (18u << 20)); // 16 MB

    (void)hipFuncSetAttribute((const void*)gemm_kernel,
                              hipFuncAttributeMaxDynamicSharedMemorySize, NBUF * TILEB);

    conv_kernel<<<4096 + 512, 256, 0, stream>>>(x, wgt, A, Bt);
    gemm_kernel<<<(NTOK / BM) * (NOUT / BN), 512, NBUF * TILEB, stream>>>(A, Bt, Y);
    epilogue_kernel<<<NTOK, 256, 0, stream>>>(Y, out);
}